// Round 1
// baseline (2466.065 us; speedup 1.0000x reference)
//
#include <hip/hip_runtime.h>
#include <hip/hip_bf16.h>
#include <cstdint>

// D = 512 everywhere (FIN = HID = OUT = 512)

// ---- init: every row of D gets `bias` (512 floats = 128 float4) ----
__global__ __launch_bounds__(256) void init_rows_kernel(
    float* __restrict__ D, const float* __restrict__ bias, long total4)
{
    long i = (long)blockIdx.x * 256 + threadIdx.x;
    if (i >= total4) return;
    ((float4*)D)[i] = ((const float4*)bias)[i & 127];
}

// ---- fp32 GEMM: C[M,512] = op(A)[M,512] @ B[512,512](row-major) ----
// MODE 0: C = A@B
// MODE 1: C = relu(A)@B
// MODE 2: C = leaky_relu(relu(A)@B + cadd[graph(row)])
template<int MODE>
__global__ __launch_bounds__(256) void gemm512_kernel(
    const float* __restrict__ A, const float* __restrict__ B,
    float* __restrict__ C, const float* __restrict__ cadd, int nPerGraph)
{
    __shared__ float As[64][20];   // 64 rows x 16 k, pad to 20 (80B: 16B-aligned rows, conflict-spread)
    __shared__ float Bs[16][64];

    const int t  = threadIdx.x;
    const int tx = t & 15, ty = t >> 4;
    const int bn = blockIdx.x;     // 0..7   (inner: W tile reused from L2 across bm)
    const int bm = blockIdx.y;     // 0..M/64-1

    const float* Ablk = A + (size_t)bm * 64 * 512;
    const float* Bblk = B + bn * 64;

    float acc[4][4] = {{0.f,0.f,0.f,0.f},{0.f,0.f,0.f,0.f},
                       {0.f,0.f,0.f,0.f},{0.f,0.f,0.f,0.f}};

    const int ra = t >> 2, ka = (t & 3) * 4;   // A stage: row, k-offset (float4)
    const int kb = t >> 4, cb = (t & 15) * 4;  // B stage: k-row, col-offset (float4)

    for (int k0 = 0; k0 < 512; k0 += 16) {
        float4 av = *(const float4*)(Ablk + (size_t)ra * 512 + k0 + ka);
        if (MODE >= 1) {
            av.x = fmaxf(av.x, 0.f); av.y = fmaxf(av.y, 0.f);
            av.z = fmaxf(av.z, 0.f); av.w = fmaxf(av.w, 0.f);
        }
        float4 bv = *(const float4*)(Bblk + (size_t)(k0 + kb) * 512 + cb);
        *(float4*)&As[ra][ka] = av;
        *(float4*)&Bs[kb][cb] = bv;
        __syncthreads();

        #pragma unroll
        for (int kq = 0; kq < 4; kq++) {
            float a[4][4];
            #pragma unroll
            for (int i = 0; i < 4; i++)
                *(float4*)&a[i][0] = *(const float4*)&As[ty * 4 + i][kq * 4];
            #pragma unroll
            for (int kk = 0; kk < 4; kk++) {
                float4 b4 = *(const float4*)&Bs[kq * 4 + kk][tx * 4];
                #pragma unroll
                for (int i = 0; i < 4; i++) {
                    acc[i][0] = fmaf(a[i][kk], b4.x, acc[i][0]);
                    acc[i][1] = fmaf(a[i][kk], b4.y, acc[i][1]);
                    acc[i][2] = fmaf(a[i][kk], b4.z, acc[i][2]);
                    acc[i][3] = fmaf(a[i][kk], b4.w, acc[i][3]);
                }
            }
        }
        __syncthreads();
    }

    const int row0 = bm * 64 + ty * 4;
    const int col0 = bn * 64 + tx * 4;
    float4 cv = make_float4(0.f, 0.f, 0.f, 0.f);
    if (MODE == 2)
        cv = *(const float4*)(cadd + (size_t)((bm * 64) / nPerGraph) * 512 + col0);

    #pragma unroll
    for (int i = 0; i < 4; i++) {
        float4 v;
        v.x = acc[i][0]; v.y = acc[i][1]; v.z = acc[i][2]; v.w = acc[i][3];
        if (MODE == 2) {
            v.x += cv.x; v.y += cv.y; v.z += cv.z; v.w += cv.w;
            v.x = v.x > 0.f ? v.x : 0.01f * v.x;
            v.y = v.y > 0.f ? v.y : 0.01f * v.y;
            v.z = v.z > 0.f ? v.z : 0.01f * v.z;
            v.w = v.w > 0.f ? v.w : 0.01f * v.w;
        }
        *(float4*)(C + (size_t)(row0 + i) * 512 + col0) = v;
    }
}

// ---- edge scatter: D[row] += w * (S[col] (+ cadd[graph])) , atomic fp32 ----
__global__ __launch_bounds__(128) void scatter_kernel(
    const float* __restrict__ S, float* __restrict__ D,
    const int* __restrict__ rows, const int* __restrict__ cols,
    const float* __restrict__ vals, const float* __restrict__ cadd,
    int ePerGraph)
{
    const int e = blockIdx.x;
    const int row = rows[e], col = cols[e];
    const float w = vals[e];
    const int t = threadIdx.x;            // 0..127 -> one float4 each
    float4 v = *((const float4*)(S + (size_t)col * 512) + t);
    if (cadd) {
        float4 c = *((const float4*)(cadd + (size_t)(e / ePerGraph) * 512) + t);
        v.x += c.x; v.y += c.y; v.z += c.z; v.w += c.w;
    }
    float* d = D + (size_t)row * 512 + t * 4;
    atomicAdd(d + 0, w * v.x);
    atomicAdd(d + 1, w * v.y);
    atomicAdd(d + 2, w * v.z);
    atomicAdd(d + 3, w * v.w);
}

// ---- per-graph root vectors ----
// which==0: c2[g] = relu(X[root_g]) @ W2[512:1024]           (no bias; b2 goes in agg2 init)
// which==1: c3[g] = h1[root_g] @ Wl[512:1024] + bl           (h1 raw, NOT relu'd)
__global__ __launch_bounds__(256) void rootvec_kernel(
    const float* __restrict__ X, const float* __restrict__ H1,
    const int* __restrict__ root_idx,
    const float* __restrict__ W2full, const float* __restrict__ Wlfull,
    const float* __restrict__ bl,
    float* __restrict__ c2, float* __restrict__ c3)
{
    __shared__ float xs[512];
    const int g = blockIdx.x;
    const int which = blockIdx.y;
    const int t = threadIdx.x;
    const int r = root_idx[g];

    const float* src = which ? (H1 + (size_t)r * 512) : (X + (size_t)r * 512);
    const float* W = (which ? Wlfull : W2full) + 512 * 512;

    for (int k = t; k < 512; k += 256) {
        float v = src[k];
        if (which == 0) v = fmaxf(v, 0.f);
        xs[k] = v;
    }
    __syncthreads();

    float* outp = which ? c3 : c2;
    for (int oo = t; oo < 512; oo += 256) {
        float acc = which ? bl[oo] : 0.f;
        #pragma unroll 4
        for (int k = 0; k < 512; k++)
            acc = fmaf(xs[k], W[(size_t)k * 512 + oo], acc);
        outp[(size_t)g * 512 + oo] = acc;
    }
}

extern "C" void kernel_launch(void* const* d_in, const int* in_sizes, int n_in,
                              void* d_out, int out_size, void* d_ws, size_t ws_size,
                              hipStream_t stream)
{
    const float* X        = (const float*)d_in[0];
    const int*   adjs     = (const int*)d_in[1];
    const float* vals     = (const float*)d_in[2];
    const int*   root_idx = (const int*)d_in[3];
    const float* W1       = (const float*)d_in[6];
    const float* b1       = (const float*)d_in[7];
    const float* W2       = (const float*)d_in[8];
    const float* b2       = (const float*)d_in[9];
    const float* Wl       = (const float*)d_in[10];
    const float* bl       = (const float*)d_in[11];
    float* out = (float*)d_out;

    const int M    = in_sizes[0] / 512;   // 65536 total nodes
    const int Etot = in_sizes[2];         // 65536 total edges
    const int Bg   = in_sizes[3];         // 16 graphs
    const int N    = M / Bg;              // 4096 nodes/graph
    const int E    = Etot / Bg;           // 4096 edges/graph

    float* buf0 = (float*)d_ws;                    // support1 -> s2
    float* buf1 = buf0 + (size_t)M * 512;          // h1 -> agg2
    float* c2   = buf1 + (size_t)M * 512;          // [Bg,512]
    float* c3   = c2 + (size_t)Bg * 512;           // [Bg,512]

    const int* rows = adjs;          // adjs[0] = src (segment target)
    const int* cols = adjs + Etot;   // adjs[1] = dst (gather source)

    const long total4 = (long)M * 128;
    const int initBlocks = (int)((total4 + 255) / 256);
    dim3 gemmGrid(8, M / 64);

    // 1. h1 = b1 (broadcast)
    hipLaunchKernelGGL(init_rows_kernel, dim3(initBlocks), dim3(256), 0, stream,
                       buf1, b1, total4);
    // 2. support1 = X @ W1
    hipLaunchKernelGGL(gemm512_kernel<0>, gemmGrid, dim3(256), 0, stream,
                       X, W1, buf0, (const float*)nullptr, N);
    // 3. h1 += scatter(w * support1[col] -> row)
    hipLaunchKernelGGL(scatter_kernel, dim3(Etot), dim3(128), 0, stream,
                       buf0, buf1, rows, cols, vals, (const float*)nullptr, E);
    // 4. c2 = relu(X[root]) @ W2b ; c3 = h1[root] @ Wlb + bl
    hipLaunchKernelGGL(rootvec_kernel, dim3(Bg, 2), dim3(256), 0, stream,
                       X, buf1, root_idx, W2, Wl, bl, c2, c3);
    // 5. s2 = relu(h1) @ W2a
    hipLaunchKernelGGL(gemm512_kernel<1>, gemmGrid, dim3(256), 0, stream,
                       buf1, W2, buf0, (const float*)nullptr, N);
    // 6. agg2 = b2 (broadcast)  [h1 dead: c3 captured, gemm2 done]
    hipLaunchKernelGGL(init_rows_kernel, dim3(initBlocks), dim3(256), 0, stream,
                       buf1, b2, total4);
    // 7. agg2 += scatter(w * (s2[col] + c2[g]) -> row)
    hipLaunchKernelGGL(scatter_kernel, dim3(Etot), dim3(128), 0, stream,
                       buf0, buf1, rows, cols, vals, c2, E);
    // 8. out = leaky_relu(relu(agg2) @ Wla + c3[g])
    hipLaunchKernelGGL(gemm512_kernel<2>, gemmGrid, dim3(256), 0, stream,
                       buf1, Wl, out, c3, N);
}

// Round 2
// 637.360 us; speedup vs baseline: 3.8692x; 3.8692x over previous
//
#include <hip/hip_runtime.h>
#include <hip/hip_bf16.h>
#include <cstdint>

typedef unsigned int uint32;
typedef unsigned short ushort16;
typedef __attribute__((ext_vector_type(8))) short short8;   // 8 bf16 (4 VGPRs)
typedef __attribute__((ext_vector_type(4))) float f32x4;

// fp32 -> bf16 round-to-nearest-even (finite inputs)
__device__ __forceinline__ ushort16 f2bf(float f) {
    uint32 u = __float_as_uint(f);
    u += 0x7fffu + ((u >> 16) & 1u);
    return (ushort16)(u >> 16);
}
__device__ __forceinline__ uint32 packbf2(float lo, float hi) {
    return (uint32)f2bf(lo) | ((uint32)f2bf(hi) << 16);
}

// ---------------- weight convert + transpose: Wt[n][k] = bf16(W[k][n]) ----------------
// grid (16,16,3), block 256 (32x8). Each z handles one 512x512 matrix.
__global__ __launch_bounds__(256) void convertW_kernel(
    const float* __restrict__ W1, const float* __restrict__ W2,
    const float* __restrict__ Wl, ushort16* __restrict__ Wt)
{
    const float* src = blockIdx.z == 0 ? W1 : (blockIdx.z == 1 ? W2 : Wl);
    ushort16* dst = Wt + (size_t)blockIdx.z * 512 * 512;
    __shared__ ushort16 tile[32][33];
    const int n0 = blockIdx.x * 32, k0 = blockIdx.y * 32;
    const int tx = threadIdx.x & 31, ty = threadIdx.x >> 5;
    #pragma unroll
    for (int j = 0; j < 32; j += 8)
        tile[ty + j][tx] = f2bf(src[(size_t)(k0 + ty + j) * 512 + n0 + tx]);
    __syncthreads();
    #pragma unroll
    for (int j = 0; j < 32; j += 8)
        dst[(size_t)(n0 + ty + j) * 512 + k0 + tx] = tile[tx][ty + j];
}

// ---------------- CSR build ----------------
__global__ __launch_bounds__(256) void zero_kernel(int* __restrict__ p, int n) {
    int i = blockIdx.x * 256 + threadIdx.x;
    if (i < n) p[i] = 0;
}
__global__ __launch_bounds__(256) void hist_kernel(
    const int* __restrict__ rows, int* __restrict__ deg, int E)
{
    int e = blockIdx.x * 256 + threadIdx.x;
    if (e < E) atomicAdd(&deg[rows[e]], 1);
}
// per-block exclusive scan of 256 ints; bsum[b] = block total
__global__ __launch_bounds__(256) void scan_block_kernel(
    const int* __restrict__ deg, int* __restrict__ offs, int* __restrict__ bsum)
{
    __shared__ int s[256];
    const int t = threadIdx.x, i = blockIdx.x * 256 + t;
    int v = deg[i];
    s[t] = v; __syncthreads();
    for (int off = 1; off < 256; off <<= 1) {
        int x = (t >= off) ? s[t - off] : 0;
        __syncthreads();
        s[t] += x;
        __syncthreads();
    }
    offs[i] = s[t] - v;
    if (t == 255) bsum[blockIdx.x] = s[t];
}
// exclusive scan of the 256 block sums, in place
__global__ __launch_bounds__(256) void scan_top_kernel(int* __restrict__ bsum)
{
    __shared__ int s[256];
    const int t = threadIdx.x;
    int v = bsum[t];
    s[t] = v; __syncthreads();
    for (int off = 1; off < 256; off <<= 1) {
        int x = (t >= off) ? s[t - off] : 0;
        __syncthreads();
        s[t] += x;
        __syncthreads();
    }
    bsum[t] = s[t] - v;
}
__global__ __launch_bounds__(256) void scan_add_kernel(
    int* __restrict__ offs, const int* __restrict__ bsum)
{
    offs[blockIdx.x * 256 + threadIdx.x] += bsum[blockIdx.x];
}
__global__ __launch_bounds__(256) void fill_kernel(
    const int* __restrict__ rows, const int* __restrict__ cols,
    const float* __restrict__ vals, const int* __restrict__ offs,
    int* __restrict__ cursor, int* __restrict__ ecol, float* __restrict__ ew, int E)
{
    int e = blockIdx.x * 256 + threadIdx.x;
    if (e >= E) return;
    int r = rows[e];
    int p = atomicAdd(&cursor[r], 1);
    int s = offs[r] + p;
    ecol[s] = cols[e];
    ew[s] = vals[e];
}

// ---------------- CSR gather: D[row] = bias + sum_j w_j*S[col_j] (+ (sum w)*cadd[g]) ----
template<int WITHC>
__global__ __launch_bounds__(128) void gather_kernel(
    const float* __restrict__ S, float* __restrict__ D,
    const int* __restrict__ offs, const int* __restrict__ deg,
    const int* __restrict__ ecol, const float* __restrict__ ew,
    const float* __restrict__ bias, const float* __restrict__ cadd, int nPerGraph)
{
    const int row = blockIdx.x, t = threadIdx.x;   // 128 threads: one float4 each
    const float4* S4 = (const float4*)S;
    float4 acc = ((const float4*)bias)[t];
    const int start = offs[row], d = deg[row];
    float sw = 0.f;
    for (int j = 0; j < d; j++) {
        int col = ecol[start + j];
        float w = ew[start + j];
        float4 s = S4[(size_t)col * 128 + t];
        acc.x = fmaf(w, s.x, acc.x);
        acc.y = fmaf(w, s.y, acc.y);
        acc.z = fmaf(w, s.z, acc.z);
        acc.w = fmaf(w, s.w, acc.w);
        sw += w;
    }
    if (WITHC) {
        float4 c = ((const float4*)cadd)[(size_t)(row / nPerGraph) * 128 + t];
        acc.x = fmaf(sw, c.x, acc.x);
        acc.y = fmaf(sw, c.y, acc.y);
        acc.z = fmaf(sw, c.z, acc.z);
        acc.w = fmaf(sw, c.w, acc.w);
    }
    ((float4*)D)[(size_t)row * 128 + t] = acc;
}

// ---------------- bf16 MFMA GEMM: C[M,512] = op(A_fp32)[M,512] @ Wt^T ----------------
// Wt is [n][k] bf16 (pre-transposed). Tile 128x128, BK=32, 4 waves in 2x2.
// MODE 0: C = A@W ; MODE 1: C = relu(A)@W ; MODE 2: C = leaky(relu(A)@W + cadd[g])
template<int MODE>
__global__ __launch_bounds__(256) void gemm_mfma_kernel(
    const float* __restrict__ A, const ushort16* __restrict__ Bt,
    float* __restrict__ C, const float* __restrict__ cadd, int nPerGraph)
{
    __shared__ ushort16 As[128 * 40];   // 128 rows x 32 k bf16, pad to 40 (80B rows)
    __shared__ ushort16 Bs[128 * 40];   // 128 n   x 32 k bf16, pad to 40

    const int t = threadIdx.x;
    const int bn = blockIdx.x;          // 0..3
    const int bm = blockIdx.y;          // 0..M/128-1
    const int lane = t & 63, wave = t >> 6;
    const int wm = wave >> 1, wn = wave & 1;          // 2x2 wave grid (64x64 each)
    const int quad = lane >> 4, l16 = lane & 15;
    const int sr = t >> 1, sc = (t & 1) * 16;         // staging: row, 16-elem chunk

    const float*    Ap = A + (size_t)(bm * 128 + sr) * 512 + sc;
    const ushort16* Bp = Bt + (size_t)(bn * 128 + sr) * 512 + sc;
    ushort16* Asw = &As[sr * 40 + sc];
    ushort16* Bsw = &Bs[sr * 40 + sc];

    f32x4 acc[4][4];
    #pragma unroll
    for (int i = 0; i < 4; i++)
        #pragma unroll
        for (int j = 0; j < 4; j++)
            acc[i][j] = (f32x4){0.f, 0.f, 0.f, 0.f};

    for (int k0 = 0; k0 < 512; k0 += 32) {
        float4 a0 = *(const float4*)(Ap + k0);
        float4 a1 = *(const float4*)(Ap + k0 + 4);
        float4 a2 = *(const float4*)(Ap + k0 + 8);
        float4 a3 = *(const float4*)(Ap + k0 + 12);
        uint4 bv0 = *(const uint4*)(Bp + k0);
        uint4 bv1 = *(const uint4*)(Bp + k0 + 8);
        if (MODE >= 1) {
            a0.x = fmaxf(a0.x, 0.f); a0.y = fmaxf(a0.y, 0.f); a0.z = fmaxf(a0.z, 0.f); a0.w = fmaxf(a0.w, 0.f);
            a1.x = fmaxf(a1.x, 0.f); a1.y = fmaxf(a1.y, 0.f); a1.z = fmaxf(a1.z, 0.f); a1.w = fmaxf(a1.w, 0.f);
            a2.x = fmaxf(a2.x, 0.f); a2.y = fmaxf(a2.y, 0.f); a2.z = fmaxf(a2.z, 0.f); a2.w = fmaxf(a2.w, 0.f);
            a3.x = fmaxf(a3.x, 0.f); a3.y = fmaxf(a3.y, 0.f); a3.z = fmaxf(a3.z, 0.f); a3.w = fmaxf(a3.w, 0.f);
        }
        uint4 w0, w1;
        w0.x = packbf2(a0.x, a0.y); w0.y = packbf2(a0.z, a0.w);
        w0.z = packbf2(a1.x, a1.y); w0.w = packbf2(a1.z, a1.w);
        w1.x = packbf2(a2.x, a2.y); w1.y = packbf2(a2.z, a2.w);
        w1.z = packbf2(a3.x, a3.y); w1.w = packbf2(a3.z, a3.w);
        *(uint4*)Asw = w0;
        *(uint4*)(Asw + 8) = w1;
        *(uint4*)Bsw = bv0;
        *(uint4*)(Bsw + 8) = bv1;
        __syncthreads();

        short8 af[4], bf[4];
        #pragma unroll
        for (int mi = 0; mi < 4; mi++)
            af[mi] = *(const short8*)&As[(wm * 64 + mi * 16 + l16) * 40 + quad * 8];
        #pragma unroll
        for (int ni = 0; ni < 4; ni++)
            bf[ni] = *(const short8*)&Bs[(wn * 64 + ni * 16 + l16) * 40 + quad * 8];
        #pragma unroll
        for (int mi = 0; mi < 4; mi++)
            #pragma unroll
            for (int ni = 0; ni < 4; ni++)
                acc[mi][ni] = __builtin_amdgcn_mfma_f32_16x16x32_bf16(
                    af[mi], bf[ni], acc[mi][ni], 0, 0, 0);
        __syncthreads();
    }

    const int g = (MODE == 2) ? (bm * 128) / nPerGraph : 0;
    #pragma unroll
    for (int ni = 0; ni < 4; ni++) {
        const int col = bn * 128 + wn * 64 + ni * 16 + l16;
        const float cv = (MODE == 2) ? cadd[(size_t)g * 512 + col] : 0.f;
        #pragma unroll
        for (int mi = 0; mi < 4; mi++) {
            const int row0 = bm * 128 + wm * 64 + mi * 16 + quad * 4;
            #pragma unroll
            for (int r = 0; r < 4; r++) {
                float v = acc[mi][ni][r];
                if (MODE == 2) { v += cv; v = v > 0.f ? v : 0.01f * v; }
                C[(size_t)(row0 + r) * 512 + col] = v;
            }
        }
    }
}

// ---------------- per-graph root vectors (fp32, small) ----------------
// which==0: c2[g] = relu(X[root_g]) @ W2[512:1024]
// which==1: c3[g] = h1[root_g] @ Wl[512:1024] + bl
__global__ __launch_bounds__(256) void rootvec_kernel(
    const float* __restrict__ X, const float* __restrict__ H1,
    const int* __restrict__ root_idx,
    const float* __restrict__ W2full, const float* __restrict__ Wlfull,
    const float* __restrict__ bl,
    float* __restrict__ c2, float* __restrict__ c3)
{
    __shared__ float xs[512];
    __shared__ float red[4][64];
    const int g = blockIdx.x, which = blockIdx.y, chunk = blockIdx.z;
    const int t = threadIdx.x;
    const int r = root_idx[g];
    const float* src = which ? (H1 + (size_t)r * 512) : (X + (size_t)r * 512);
    const float* W = (which ? Wlfull : W2full) + 512 * 512;

    for (int k = t; k < 512; k += 256) {
        float v = src[k];
        if (which == 0) v = fmaxf(v, 0.f);
        xs[k] = v;
    }
    __syncthreads();

    const int col = chunk * 64 + (t & 63), kg = t >> 6;
    float acc = 0.f;
    #pragma unroll 4
    for (int k = kg * 128; k < kg * 128 + 128; k++)
        acc = fmaf(xs[k], W[(size_t)k * 512 + col], acc);
    red[kg][t & 63] = acc;
    __syncthreads();
    if (t < 64) {
        float s = red[0][t] + red[1][t] + red[2][t] + red[3][t];
        int c = chunk * 64 + t;
        if (which) c3[(size_t)g * 512 + c] = s + bl[c];
        else       c2[(size_t)g * 512 + c] = s;
    }
}

extern "C" void kernel_launch(void* const* d_in, const int* in_sizes, int n_in,
                              void* d_out, int out_size, void* d_ws, size_t ws_size,
                              hipStream_t stream)
{
    const float* X        = (const float*)d_in[0];
    const int*   adjs     = (const int*)d_in[1];
    const float* vals     = (const float*)d_in[2];
    const int*   root_idx = (const int*)d_in[3];
    const float* W1       = (const float*)d_in[6];
    const float* b1       = (const float*)d_in[7];
    const float* W2       = (const float*)d_in[8];
    const float* b2       = (const float*)d_in[9];
    const float* Wl       = (const float*)d_in[10];
    const float* bl       = (const float*)d_in[11];
    float* out = (float*)d_out;

    const int M    = in_sizes[0] / 512;   // 65536 nodes total
    const int Etot = in_sizes[2];         // 65536 edges total
    const int Bg   = in_sizes[3];         // 16 graphs
    const int N    = M / Bg;              // 4096 nodes/graph

    // workspace layout (bufB == d_out is the GEMM-output ping buffer)
    float*    bufA   = (float*)d_ws;                       // h1 / agg2 (gather out)
    ushort16* Wt     = (ushort16*)(bufA + (size_t)M * 512);// 3 x 512x512 bf16 transposed
    float*    c2     = (float*)(Wt + 3 * 512 * 512);
    float*    c3     = c2 + (size_t)Bg * 512;
    int*      deg    = (int*)(c3 + (size_t)Bg * 512);
    int*      cursor = deg + M;
    int*      offs   = cursor + M;
    int*      bsum   = offs + M;
    int*      ecol   = bsum + 256;
    float*    ew     = (float*)(ecol + Etot);
    float*    bufB   = out;

    const int* rows = adjs;          // adjs[0] = src (segment target)
    const int* cols = adjs + Etot;   // adjs[1] = dst (gather source)

    const int eBlocks = (Etot + 255) / 256;
    dim3 gemmGrid(4, M / 128);

    // --- weights -> bf16 transposed ---
    convertW_kernel<<<dim3(16, 16, 3), 256, 0, stream>>>(W1, W2, Wl, Wt);

    // --- CSR build (edges shared by both scatters) ---
    zero_kernel<<<(2 * M + 255) / 256, 256, 0, stream>>>(deg, 2 * M);   // deg + cursor
    hist_kernel<<<eBlocks, 256, 0, stream>>>(rows, deg, Etot);
    scan_block_kernel<<<M / 256, 256, 0, stream>>>(deg, offs, bsum);
    scan_top_kernel<<<1, 256, 0, stream>>>(bsum);
    scan_add_kernel<<<M / 256, 256, 0, stream>>>(offs, bsum);
    fill_kernel<<<eBlocks, 256, 0, stream>>>(rows, cols, vals, offs, cursor, ecol, ew, Etot);

    // --- 1. support1 = X @ W1 -> bufB ---
    gemm_mfma_kernel<0><<<gemmGrid, 256, 0, stream>>>(X, Wt, bufB, (const float*)nullptr, N);
    // --- 2. h1 = b1 + gather(w * support1[col]) -> bufA ---
    gather_kernel<0><<<M, 128, 0, stream>>>(bufB, bufA, offs, deg, ecol, ew, b1,
                                            (const float*)nullptr, N);
    // --- 3. root vectors: c2 (from X), c3 (from h1) ---
    rootvec_kernel<<<dim3(Bg, 2, 8), 256, 0, stream>>>(X, bufA, root_idx, W2, Wl, bl, c2, c3);
    // --- 4. s2 = relu(h1) @ W2a -> bufB ---
    gemm_mfma_kernel<1><<<gemmGrid, 256, 0, stream>>>(bufA, Wt + (size_t)512 * 512, bufB,
                                                      (const float*)nullptr, N);
    // --- 5. agg2 = b2 + sumw*c2[g] + gather(w * s2[col]) -> bufA ---
    gather_kernel<1><<<M, 128, 0, stream>>>(bufB, bufA, offs, deg, ecol, ew, b2, c2, N);
    // --- 6. out = leaky(relu(agg2) @ Wla + c3[g]) -> d_out ---
    gemm_mfma_kernel<2><<<gemmGrid, 256, 0, stream>>>(bufA, Wt + (size_t)2 * 512 * 512, out, c3, N);
}

// Round 3
// 481.127 us; speedup vs baseline: 5.1256x; 1.3247x over previous
//
#include <hip/hip_runtime.h>
#include <hip/hip_bf16.h>
#include <cstdint>

typedef unsigned int uint32;
typedef unsigned short ushort16;
typedef __attribute__((ext_vector_type(8))) short short8;   // 8 bf16 (4 VGPRs)
typedef __attribute__((ext_vector_type(4))) float f32x4;

// fp32 -> bf16 round-to-nearest-even (finite inputs)
__device__ __forceinline__ ushort16 f2bf(float f) {
    uint32 u = __float_as_uint(f);
    u += 0x7fffu + ((u >> 16) & 1u);
    return (ushort16)(u >> 16);
}
__device__ __forceinline__ uint32 packbf2(float lo, float hi) {
    return (uint32)f2bf(lo) | ((uint32)f2bf(hi) << 16);
}
__device__ __forceinline__ float bf_lo(uint32 u) { return __uint_as_float(u << 16); }
__device__ __forceinline__ float bf_hi(uint32 u) { return __uint_as_float(u & 0xffff0000u); }

// async global->LDS, 16B per lane; LDS dest = wave-uniform base + lane*16
__device__ __forceinline__ void gload_lds16(const void* g, void* l) {
    __builtin_amdgcn_global_load_lds(
        (const __attribute__((address_space(1))) uint32*)g,
        (__attribute__((address_space(3))) uint32*)l, 16, 0, 0);
}

// ---------------- weight convert + transpose: Wt[n][k] = bf16(W[k][n]) ----------------
__global__ __launch_bounds__(256) void convertW_kernel(
    const float* __restrict__ W1, const float* __restrict__ W2,
    const float* __restrict__ Wl, ushort16* __restrict__ Wt)
{
    const float* src = blockIdx.z == 0 ? W1 : (blockIdx.z == 1 ? W2 : Wl);
    ushort16* dst = Wt + (size_t)blockIdx.z * 512 * 512;
    __shared__ ushort16 tile[32][33];
    const int n0 = blockIdx.x * 32, k0 = blockIdx.y * 32;
    const int tx = threadIdx.x & 31, ty = threadIdx.x >> 5;
    #pragma unroll
    for (int j = 0; j < 32; j += 8)
        tile[ty + j][tx] = f2bf(src[(size_t)(k0 + ty + j) * 512 + n0 + tx]);
    __syncthreads();
    #pragma unroll
    for (int j = 0; j < 32; j += 8)
        dst[(size_t)(n0 + ty + j) * 512 + k0 + tx] = tile[tx][ty + j];
}

// ---------------- CSR build ----------------
__global__ __launch_bounds__(256) void zero_kernel(int* __restrict__ p, int n) {
    int i = blockIdx.x * 256 + threadIdx.x;
    if (i < n) p[i] = 0;
}
__global__ __launch_bounds__(256) void hist_kernel(
    const int* __restrict__ rows, int* __restrict__ deg, int E)
{
    int e = blockIdx.x * 256 + threadIdx.x;
    if (e < E) atomicAdd(&deg[rows[e]], 1);
}
__global__ __launch_bounds__(256) void scan_block_kernel(
    const int* __restrict__ deg, int* __restrict__ offs, int* __restrict__ bsum)
{
    __shared__ int s[256];
    const int t = threadIdx.x, i = blockIdx.x * 256 + t;
    int v = deg[i];
    s[t] = v; __syncthreads();
    for (int off = 1; off < 256; off <<= 1) {
        int x = (t >= off) ? s[t - off] : 0;
        __syncthreads();
        s[t] += x;
        __syncthreads();
    }
    offs[i] = s[t] - v;
    if (t == 255) bsum[blockIdx.x] = s[t];
}
__global__ __launch_bounds__(256) void scan_top_kernel(int* __restrict__ bsum)
{
    __shared__ int s[256];
    const int t = threadIdx.x;
    int v = bsum[t];
    s[t] = v; __syncthreads();
    for (int off = 1; off < 256; off <<= 1) {
        int x = (t >= off) ? s[t - off] : 0;
        __syncthreads();
        s[t] += x;
        __syncthreads();
    }
    bsum[t] = s[t] - v;
}
__global__ __launch_bounds__(256) void scan_add_kernel(
    int* __restrict__ offs, const int* __restrict__ bsum)
{
    offs[blockIdx.x * 256 + threadIdx.x] += bsum[blockIdx.x];
}
__global__ __launch_bounds__(256) void fill_kernel(
    const int* __restrict__ rows, const int* __restrict__ cols,
    const float* __restrict__ vals, const int* __restrict__ offs,
    int* __restrict__ cursor, int* __restrict__ ecol, float* __restrict__ ew, int E)
{
    int e = blockIdx.x * 256 + threadIdx.x;
    if (e >= E) return;
    int r = rows[e];
    int p = atomicAdd(&cursor[r], 1);
    int s = offs[r] + p;
    ecol[s] = cols[e];
    ew[s] = vals[e];
}

// ---- CSR gather (bf16 in/out, fp32 accum): D[row]=relu(bias + Σ w*S[col] (+Σw*c[g])) ----
// one wave per row; lane covers 8 bf16 (16B). SAVEROOT: stash raw fp32 row for roots.
template<int WITHC, int SAVEROOT>
__global__ __launch_bounds__(256) void gather_kernel(
    const ushort16* __restrict__ S, ushort16* __restrict__ D,
    const int* __restrict__ offs, const int* __restrict__ deg,
    const int* __restrict__ ecol, const float* __restrict__ ew,
    const float* __restrict__ bias, const float* __restrict__ cadd,
    const int* __restrict__ root_idx, float* __restrict__ hroot, int nPerGraph)
{
    const int wave = threadIdx.x >> 6, l = threadIdx.x & 63;
    const int row = blockIdx.x * 4 + wave;
    const uint4* S4 = (const uint4*)S;     // 64 x uint4 per row
    float acc[8];
    {
        float4 b0 = ((const float4*)bias)[l * 2];
        float4 b1 = ((const float4*)bias)[l * 2 + 1];
        acc[0] = b0.x; acc[1] = b0.y; acc[2] = b0.z; acc[3] = b0.w;
        acc[4] = b1.x; acc[5] = b1.y; acc[6] = b1.z; acc[7] = b1.w;
    }
    const int start = offs[row], d = deg[row];
    float sw = 0.f;
    for (int j = 0; j < d; j++) {
        int col = ecol[start + j];
        float w = ew[start + j];
        uint4 s = S4[(size_t)col * 64 + l];
        acc[0] = fmaf(w, bf_lo(s.x), acc[0]); acc[1] = fmaf(w, bf_hi(s.x), acc[1]);
        acc[2] = fmaf(w, bf_lo(s.y), acc[2]); acc[3] = fmaf(w, bf_hi(s.y), acc[3]);
        acc[4] = fmaf(w, bf_lo(s.z), acc[4]); acc[5] = fmaf(w, bf_hi(s.z), acc[5]);
        acc[6] = fmaf(w, bf_lo(s.w), acc[6]); acc[7] = fmaf(w, bf_hi(s.w), acc[7]);
        sw += w;
    }
    if (WITHC) {
        const float* c = cadd + (size_t)(row / nPerGraph) * 512 + l * 8;
        #pragma unroll
        for (int i = 0; i < 8; i++) acc[i] = fmaf(sw, c[i], acc[i]);
    }
    if (SAVEROOT) {
        int g = row / nPerGraph;
        if (row == root_idx[g]) {
            float* hr = hroot + (size_t)g * 512 + l * 8;
            #pragma unroll
            for (int i = 0; i < 8; i++) hr[i] = acc[i];   // raw (pre-relu) fp32
        }
    }
    uint4 o;
    o.x = packbf2(fmaxf(acc[0], 0.f), fmaxf(acc[1], 0.f));
    o.y = packbf2(fmaxf(acc[2], 0.f), fmaxf(acc[3], 0.f));
    o.z = packbf2(fmaxf(acc[4], 0.f), fmaxf(acc[5], 0.f));
    o.w = packbf2(fmaxf(acc[6], 0.f), fmaxf(acc[7], 0.f));
    ((uint4*)D)[(size_t)row * 64 + l] = o;
}

// ---------------- bf16 MFMA GEMM: C[M,512] = A[M,512] @ Wt^T ----------------
// Wt: [n][k] bf16. Tile 128x128, BK=32, 4 waves 2x2. XCD swizzle: 4 bn-blocks of one
// bm are ids 8 apart -> same XCD -> A-tile fetched once per XCD L2.
// AMODE 0: A fp32 (register convert). AMODE 1: A bf16 via global_load_lds.
// CMODE 0: C bf16. CMODE 1: C fp32, += cadd[g], leaky_relu.
template<int AMODE, int CMODE>
__global__ __launch_bounds__(256) void gemm_mfma_kernel(
    const void* __restrict__ Avoid, const ushort16* __restrict__ Bt,
    void* __restrict__ Cvoid, const float* __restrict__ cadd, int nPerGraph)
{
    __shared__ __align__(16) ushort16 As[128 * 32];
    __shared__ __align__(16) ushort16 Bs[128 * 32];

    const int t = threadIdx.x;
    const int id = blockIdx.x;
    const int bm = (id >> 5) * 8 + (id & 7);
    const int bn = (id >> 3) & 3;
    const int lane = t & 63, wave = t >> 6;
    const int wm = wave >> 1, wn = wave & 1;
    const int quad = lane >> 4, l16 = lane & 15;
    const int grow = lane >> 2, gkc = (lane & 3) * 8;   // glds: row-in-seg, k-chunk
    const int sr = t >> 1, sh = (t & 1) * 16;           // fp32 staging: row, k-half

    const float*    Af = (const float*)Avoid;
    const ushort16* Ab = (const ushort16*)Avoid;
    const ushort16* Bbase = Bt + (size_t)(bn * 128) * 512;

    f32x4 acc[4][4];
    #pragma unroll
    for (int i = 0; i < 4; i++)
        #pragma unroll
        for (int j = 0; j < 4; j++)
            acc[i][j] = (f32x4){0.f, 0.f, 0.f, 0.f};

    for (int k0 = 0; k0 < 512; k0 += 32) {
        if (AMODE == 0) {
            const float* ap = Af + (size_t)(bm * 128 + sr) * 512 + k0 + sh;
            float4 a0 = *(const float4*)(ap);
            float4 a1 = *(const float4*)(ap + 4);
            float4 a2 = *(const float4*)(ap + 8);
            float4 a3 = *(const float4*)(ap + 12);
            uint4 w0, w1;
            w0.x = packbf2(a0.x, a0.y); w0.y = packbf2(a0.z, a0.w);
            w0.z = packbf2(a1.x, a1.y); w0.w = packbf2(a1.z, a1.w);
            w1.x = packbf2(a2.x, a2.y); w1.y = packbf2(a2.z, a2.w);
            w1.z = packbf2(a3.x, a3.y); w1.w = packbf2(a3.z, a3.w);
            *(uint4*)&As[sr * 32 + sh] = w0;
            *(uint4*)&As[sr * 32 + sh + 8] = w1;
        } else {
            #pragma unroll
            for (int j = 0; j < 2; j++) {
                int seg = wave * 2 + j;
                gload_lds16(Ab + (size_t)(bm * 128 + seg * 16 + grow) * 512 + k0 + gkc,
                            &As[seg * 512 + lane * 8]);
            }
        }
        #pragma unroll
        for (int j = 0; j < 2; j++) {
            int seg = wave * 2 + j;
            gload_lds16(Bbase + (size_t)(seg * 16 + grow) * 512 + k0 + gkc,
                        &Bs[seg * 512 + lane * 8]);
        }
        __syncthreads();

        short8 af[4], bfr[4];
        #pragma unroll
        for (int mi = 0; mi < 4; mi++)
            af[mi] = *(const short8*)&As[(wm * 64 + mi * 16 + l16) * 32 + quad * 8];
        #pragma unroll
        for (int ni = 0; ni < 4; ni++)
            bfr[ni] = *(const short8*)&Bs[(wn * 64 + ni * 16 + l16) * 32 + quad * 8];
        #pragma unroll
        for (int mi = 0; mi < 4; mi++)
            #pragma unroll
            for (int ni = 0; ni < 4; ni++)
                acc[mi][ni] = __builtin_amdgcn_mfma_f32_16x16x32_bf16(
                    af[mi], bfr[ni], acc[mi][ni], 0, 0, 0);
        __syncthreads();
    }

    if (CMODE == 0) {
        ushort16* C2 = (ushort16*)Cvoid;
        #pragma unroll
        for (int ni = 0; ni < 4; ni++) {
            const int col = bn * 128 + wn * 64 + ni * 16 + l16;
            #pragma unroll
            for (int mi = 0; mi < 4; mi++) {
                const int row0 = bm * 128 + wm * 64 + mi * 16 + quad * 4;
                #pragma unroll
                for (int r = 0; r < 4; r++)
                    C2[(size_t)(row0 + r) * 512 + col] = f2bf(acc[mi][ni][r]);
            }
        }
    } else {
        float* Cf = (float*)Cvoid;
        const int g = (bm * 128) / nPerGraph;
        #pragma unroll
        for (int ni = 0; ni < 4; ni++) {
            const int col = bn * 128 + wn * 64 + ni * 16 + l16;
            const float cv = cadd[(size_t)g * 512 + col];
            #pragma unroll
            for (int mi = 0; mi < 4; mi++) {
                const int row0 = bm * 128 + wm * 64 + mi * 16 + quad * 4;
                #pragma unroll
                for (int r = 0; r < 4; r++) {
                    float v = acc[mi][ni][r] + cv;
                    v = v > 0.f ? v : 0.01f * v;
                    Cf[(size_t)(row0 + r) * 512 + col] = v;
                }
            }
        }
    }
}

// ---------------- per-graph root vectors (fp32, small) ----------------
// which==0: c2[g] = relu(X[root_g]) @ W2[512:1024]
// which==1: c3[g] = hroot[g] @ Wl[512:1024] + bl     (hroot = raw fp32 h1 root rows)
__global__ __launch_bounds__(256) void rootvec_kernel(
    const float* __restrict__ X, const float* __restrict__ hroot,
    const int* __restrict__ root_idx,
    const float* __restrict__ W2full, const float* __restrict__ Wlfull,
    const float* __restrict__ bl,
    float* __restrict__ c2, float* __restrict__ c3)
{
    __shared__ float xs[512];
    __shared__ float red[4][64];
    const int g = blockIdx.x, which = blockIdx.y, chunk = blockIdx.z;
    const int t = threadIdx.x;
    const float* src = which ? (hroot + (size_t)g * 512)
                             : (X + (size_t)root_idx[g] * 512);
    const float* W = (which ? Wlfull : W2full) + 512 * 512;

    for (int k = t; k < 512; k += 256) {
        float v = src[k];
        if (which == 0) v = fmaxf(v, 0.f);
        xs[k] = v;
    }
    __syncthreads();

    const int col = chunk * 64 + (t & 63), kg = t >> 6;
    float acc = 0.f;
    #pragma unroll 4
    for (int k = kg * 128; k < kg * 128 + 128; k++)
        acc = fmaf(xs[k], W[(size_t)k * 512 + col], acc);
    red[kg][t & 63] = acc;
    __syncthreads();
    if (t < 64) {
        float s = red[0][t] + red[1][t] + red[2][t] + red[3][t];
        int c = chunk * 64 + t;
        if (which) c3[(size_t)g * 512 + c] = s + bl[c];
        else       c2[(size_t)g * 512 + c] = s;
    }
}

extern "C" void kernel_launch(void* const* d_in, const int* in_sizes, int n_in,
                              void* d_out, int out_size, void* d_ws, size_t ws_size,
                              hipStream_t stream)
{
    const float* X        = (const float*)d_in[0];
    const int*   adjs     = (const int*)d_in[1];
    const float* vals     = (const float*)d_in[2];
    const int*   root_idx = (const int*)d_in[3];
    const float* W1       = (const float*)d_in[6];
    const float* b1       = (const float*)d_in[7];
    const float* W2       = (const float*)d_in[8];
    const float* b2       = (const float*)d_in[9];
    const float* Wl       = (const float*)d_in[10];
    const float* bl       = (const float*)d_in[11];
    float* out = (float*)d_out;

    const int M    = in_sizes[0] / 512;   // 65536 nodes total
    const int Etot = in_sizes[2];         // 65536 edges total
    const int Bg   = in_sizes[3];         // 16 graphs
    const int N    = M / Bg;              // 4096 nodes/graph

    // workspace layout
    ushort16* bufS  = (ushort16*)d_ws;                     // support1 / s2 (bf16)
    ushort16* bufH  = bufS + (size_t)M * 512;              // relu(h1) / relu(agg2) (bf16)
    ushort16* Wt    = bufH + (size_t)M * 512;              // 3 x 512x512 bf16 [n][k]
    float*    c2    = (float*)(Wt + (size_t)3 * 512 * 512);
    float*    c3    = c2 + (size_t)Bg * 512;
    float*    hroot = c3 + (size_t)Bg * 512;               // raw fp32 h1 root rows
    int*      deg    = (int*)(hroot + (size_t)Bg * 512);
    int*      cursor = deg + M;
    int*      offs   = cursor + M;
    int*      bsum   = offs + M;
    int*      ecol   = bsum + 256;
    float*    ew     = (float*)(ecol + Etot);

    const int* rows = adjs;          // adjs[0] = src (segment target)
    const int* cols = adjs + Etot;   // adjs[1] = dst (gather source)

    const int eBlocks = (Etot + 255) / 256;
    dim3 gemmGrid((M / 128) * 4);    // 1-D, XCD-swizzled inside kernel

    // --- weights -> bf16 transposed ---
    convertW_kernel<<<dim3(16, 16, 3), 256, 0, stream>>>(W1, W2, Wl, Wt);

    // --- CSR build ---
    zero_kernel<<<(2 * M + 255) / 256, 256, 0, stream>>>(deg, 2 * M);   // deg + cursor
    hist_kernel<<<eBlocks, 256, 0, stream>>>(rows, deg, Etot);
    scan_block_kernel<<<M / 256, 256, 0, stream>>>(deg, offs, bsum);
    scan_top_kernel<<<1, 256, 0, stream>>>(bsum);
    scan_add_kernel<<<M / 256, 256, 0, stream>>>(offs, bsum);
    fill_kernel<<<eBlocks, 256, 0, stream>>>(rows, cols, vals, offs, cursor, ecol, ew, Etot);

    // --- 1. support1 = X @ W1 -> bufS (bf16) ---
    gemm_mfma_kernel<0, 0><<<gemmGrid, 256, 0, stream>>>(X, Wt, bufS,
                                                         (const float*)nullptr, N);
    // --- 2. bufH = relu(b1 + gather(w * support1[col])); hroot = raw root rows ---
    gather_kernel<0, 1><<<M / 4, 256, 0, stream>>>(bufS, bufH, offs, deg, ecol, ew, b1,
                                                   (const float*)nullptr, root_idx, hroot, N);
    // --- 3. root vectors: c2 (from X), c3 (from hroot) ---
    rootvec_kernel<<<dim3(Bg, 2, 8), 256, 0, stream>>>(X, hroot, root_idx, W2, Wl, bl, c2, c3);
    // --- 4. s2 = relu(h1) @ W2a -> bufS (A already relu'd bf16) ---
    gemm_mfma_kernel<1, 0><<<gemmGrid, 256, 0, stream>>>(bufH, Wt + (size_t)512 * 512, bufS,
                                                         (const float*)nullptr, N);
    // --- 5. bufH = relu(b2 + sw*c2[g] + gather(w * s2[col])) ---
    gather_kernel<1, 0><<<M / 4, 256, 0, stream>>>(bufS, bufH, offs, deg, ecol, ew, b2,
                                                   c2, root_idx, (float*)nullptr, N);
    // --- 6. out = leaky(relu(agg2) @ Wla + c3[g]) -> d_out (fp32) ---
    gemm_mfma_kernel<1, 1><<<gemmGrid, 256, 0, stream>>>(bufH, Wt + (size_t)2 * 512 * 512,
                                                         out, c3, N);
}